// Round 2
// baseline (1228.314 us; speedup 1.0000x reference)
//
#include <hip/hip_runtime.h>
#include <stdint.h>

typedef unsigned short u16;
typedef unsigned int u32;
typedef __attribute__((ext_vector_type(8))) short short8;
typedef __attribute__((ext_vector_type(4))) float f32x4;

__device__ __forceinline__ float b2f_bits(u32 bits){ union{u32 u; float f;} v; v.u=bits; return v.f; }
__device__ __forceinline__ float bf_lo(u32 w){ return b2f_bits(w<<16); }
__device__ __forceinline__ float bf_hi(u32 w){ return b2f_bits(w & 0xffff0000u); }
__device__ __forceinline__ u16 f2bf(float f){
  union{float f; u32 u;} v; v.f=f;
  return (u16)((v.u + 0x7fffu + ((v.u>>16)&1u))>>16);   // round-to-nearest-even
}

// ---------------- graph build ----------------

__global__ void zero_k(int* __restrict__ p, int n){
  int i = blockIdx.x*256 + threadIdx.x;
  if(i<n) p[i]=0;
}

// decide whether edge_index buffer is int64 (reference dtype) or int32 (harness-normalized)
__global__ void detect_k(const long long* __restrict__ ei, int* __restrict__ flag, int n, int E){
  __shared__ int sh[256];
  int t = threadIdx.x;
  int lim = E/2 < 2048 ? E/2 : 2048;   // safe to read as int64 under both layouts
  int bad = 0;
  for(int e=t; e<lim; e+=256){
    unsigned long long v = (unsigned long long)ei[e];
    if(v >= (unsigned long long)n) bad = 1;
  }
  sh[t]=bad; __syncthreads();
  for(int off=128; off>0; off>>=1){ if(t<off) sh[t] |= sh[t+off]; __syncthreads(); }
  if(t==0) *flag = sh[0];   // 1 => data is int32
}

__device__ __forceinline__ int edge_at(const void* eiv, int is32, long long idx){
  return is32 ? ((const int*)eiv)[idx] : (int)((const long long*)eiv)[idx];
}

__device__ __forceinline__ int clampi(int v, int lo, int hi){
  return v < lo ? lo : (v > hi ? hi : v);
}

__global__ void deg_k(const void* __restrict__ eiv, const int* __restrict__ flag,
                      int* __restrict__ deg, int E, int n){
  int e = blockIdx.x*256 + threadIdx.x;
  if(e>=E) return;
  int is32 = *flag;
  int r = clampi(edge_at(eiv, is32, e), 0, n-1);
  atomicAdd(&deg[r], 1);
}

__global__ void dinv_k(const int* __restrict__ deg, float* __restrict__ dinv, int n){
  int i = blockIdx.x*256 + threadIdx.x;
  if(i<n) dinv[i] = rsqrtf((float)(deg[i] + 1));   // +1: self loop (deg always > 0)
}

__global__ __launch_bounds__(256) void scan1_k(const int* __restrict__ deg, int* __restrict__ bsum, int n){
  __shared__ int sh[256];
  int b = blockIdx.x, t = threadIdx.x;
  int base = b*1024 + t*4;
  int s = 0;
  #pragma unroll
  for(int j=0;j<4;j++){ int i = base+j; if(i<n) s += deg[i]; }
  sh[t]=s; __syncthreads();
  for(int off=128; off>0; off>>=1){ if(t<off) sh[t] += sh[t+off]; __syncthreads(); }
  if(t==0) bsum[b] = sh[0];
}

__global__ __launch_bounds__(256) void scan2_k(int* __restrict__ bsum, int nb){
  __shared__ int sh[256];
  int t = threadIdx.x;
  int v = (t<nb) ? bsum[t] : 0;
  sh[t]=v; __syncthreads();
  for(int off=1; off<256; off<<=1){
    int x = (t>=off) ? sh[t-off] : 0;
    __syncthreads();
    sh[t] += x;
    __syncthreads();
  }
  if(t<nb) bsum[t] = sh[t] - v;   // exclusive
}

__global__ __launch_bounds__(256) void scan3_k(const int* __restrict__ deg, const int* __restrict__ bscan,
                        int* __restrict__ rs, int* __restrict__ cur, int n){
  __shared__ int sh[256];
  int b = blockIdx.x, t = threadIdx.x;
  int base = b*1024 + t*4;
  int v0=0,v1=0,v2=0,v3=0;
  if(base+0<n) v0=deg[base+0];
  if(base+1<n) v1=deg[base+1];
  if(base+2<n) v2=deg[base+2];
  if(base+3<n) v3=deg[base+3];
  int s = v0+v1+v2+v3;
  sh[t]=s; __syncthreads();
  for(int off=1; off<256; off<<=1){
    int x = (t>=off) ? sh[t-off] : 0;
    __syncthreads();
    sh[t] += x;
    __syncthreads();
  }
  int excl = sh[t] - s + bscan[b];
  if(base+0<n){ rs[base+0]=excl; cur[base+0]=excl; excl+=v0; }
  if(base+1<n){ rs[base+1]=excl; cur[base+1]=excl; excl+=v1; }
  if(base+2<n){ rs[base+2]=excl; cur[base+2]=excl; excl+=v2; }
  if(base+3<n){ rs[base+3]=excl; cur[base+3]=excl; excl+=v3; }
}

__global__ void scat_k(const void* __restrict__ eiv, const int* __restrict__ flag,
                       int* __restrict__ cur, int* __restrict__ csr, int E, int n){
  int e = blockIdx.x*256 + threadIdx.x;
  if(e>=E) return;
  int is32 = *flag;
  int r = clampi(edge_at(eiv, is32, e), 0, n-1);
  int c = clampi(edge_at(eiv, is32, (long long)E + e), 0, n-1);
  int pos = atomicAdd(&cur[r], 1);
  if(pos < E) csr[pos] = c;
}

// ---------------- weights prep ----------------

// pack fp32 [256][256] W into MFMA B-fragment order: [kk(8)][ct(16)][lane(64)][j(8)] bf16
__global__ void pack_k(const float* __restrict__ W, u16* __restrict__ out){
  int idx = blockIdx.x*256 + threadIdx.x;   // 65536 total
  int j  = idx & 7;
  int l  = (idx>>3) & 63;
  int ct = (idx>>9) & 15;
  int kk = idx>>13;
  int k  = kk*32 + (l>>4)*8 + j;
  int nn = ct*16 + (l&15);
  out[idx] = f2bf(W[k*256 + nn]);
}

// ---------------- propagate (3-wide, fp32) ----------------

__global__ void prop3_k(const float* __restrict__ x, const int* __restrict__ csr,
                        const int* __restrict__ rs, const int* __restrict__ deg,
                        const float* __restrict__ dinv, float* __restrict__ p0, int n){
  int i = blockIdx.x*256 + threadIdx.x;
  if(i>=n) return;
  float a0=0.f, a1=0.f, a2=0.f;
  int s = rs[i], e = s + deg[i];
  for(int t=s; t<e; t++){
    int c = csr[t];
    float w = dinv[c];
    a0 += w*x[c*3+0]; a1 += w*x[c*3+1]; a2 += w*x[c*3+2];
  }
  float di = dinv[i];
  a0 += di*x[i*3+0]; a1 += di*x[i*3+1]; a2 += di*x[i*3+2];
  p0[i*3+0]=di*a0; p0[i*3+1]=di*a1; p0[i*3+2]=di*a2;
}

// ---------------- propagate (256-wide bf16, one wave per row) ----------------

__global__ __launch_bounds__(256) void prop256_k(const u16* __restrict__ hin, u16* __restrict__ pout,
                          const int* __restrict__ csr, const int* __restrict__ rs,
                          const int* __restrict__ deg, const float* __restrict__ dinv, int n){
  int row = (blockIdx.x*256 + threadIdx.x) >> 6;
  if(row>=n) return;
  int lane = threadIdx.x & 63;
  int co = lane*4;
  const u16* hb = hin + co;
  // self contribution (norm = dinv[i]^2, h stored pre-scaled by dinv)
  uint2 sv = *(const uint2*)(hin + (size_t)row*256 + co);
  float a0=bf_lo(sv.x), a1=bf_hi(sv.x), a2=bf_lo(sv.y), a3=bf_hi(sv.y);
  int s = rs[row], end = s + deg[row];
  int e = s;
  for(; e+4<=end; e+=4){
    int c0=csr[e], c1=csr[e+1], c2=csr[e+2], c3=csr[e+3];
    uint2 v0 = *(const uint2*)(hb + (size_t)c0*256);
    uint2 v1 = *(const uint2*)(hb + (size_t)c1*256);
    uint2 v2 = *(const uint2*)(hb + (size_t)c2*256);
    uint2 v3 = *(const uint2*)(hb + (size_t)c3*256);
    a0 += bf_lo(v0.x); a1 += bf_hi(v0.x); a2 += bf_lo(v0.y); a3 += bf_hi(v0.y);
    a0 += bf_lo(v1.x); a1 += bf_hi(v1.x); a2 += bf_lo(v1.y); a3 += bf_hi(v1.y);
    a0 += bf_lo(v2.x); a1 += bf_hi(v2.x); a2 += bf_lo(v2.y); a3 += bf_hi(v2.y);
    a0 += bf_lo(v3.x); a1 += bf_hi(v3.x); a2 += bf_lo(v3.y); a3 += bf_hi(v3.y);
  }
  for(; e<end; e++){
    int c = csr[e];
    uint2 v = *(const uint2*)(hb + (size_t)c*256);
    a0 += bf_lo(v.x); a1 += bf_hi(v.x); a2 += bf_lo(v.y); a3 += bf_hi(v.y);
  }
  float sc = dinv[row];
  uint2 o;
  o.x = (u32)f2bf(a0*sc) | ((u32)f2bf(a1*sc)<<16);
  o.y = (u32)f2bf(a2*sc) | ((u32)f2bf(a3*sc)<<16);
  *(uint2*)(pout + (size_t)row*256 + co) = o;
}

// ---------------- GEMMs ----------------

// h1 = dinv * relu(p0 @ W0 + b0)  — K=3 skinny, one block per row
__global__ __launch_bounds__(256) void gemm0_k(const float* __restrict__ p0, const float* __restrict__ W0,
                        const float* __restrict__ b0, const float* __restrict__ dinv,
                        u16* __restrict__ h1, int n){
  int i = blockIdx.x;
  int j = threadIdx.x;
  float v = p0[i*3+0]*W0[j] + p0[i*3+1]*W0[256+j] + p0[i*3+2]*W0[512+j] + b0[j];
  v = fmaxf(v, 0.f) * dinv[i];
  h1[(size_t)i*256 + j] = f2bf(v);
}

// out = dinv * relu(A @ W + b), A [Mpad][256] bf16, W packed fragments.
// block = 4 waves, 64 rows; wave = 16 rows x 256 cols (16 MFMA accum tiles)
__global__ __launch_bounds__(256) void gemm256_k(const u16* __restrict__ A, const u16* __restrict__ Bp,
                          const float* __restrict__ bias, const float* __restrict__ dinv,
                          u16* __restrict__ Out, int M){
  int wave = threadIdx.x>>6, lane = threadIdx.x&63;
  int rowbase = blockIdx.x*64 + wave*16;
  f32x4 acc[16];
  #pragma unroll
  for(int t=0;t<16;t++){ acc[t][0]=0.f; acc[t][1]=0.f; acc[t][2]=0.f; acc[t][3]=0.f; }
  // A fragment: row = lane&15, k = (lane>>4)*8 + j
  const u16* Ap = A + (size_t)(rowbase + (lane&15))*256 + ((lane>>4)*8);
  const u16* Bl = Bp + (size_t)lane*8;
  #pragma unroll
  for(int kk=0; kk<8; kk++){
    short8 af = *(const short8*)(Ap + kk*32);
    const u16* bb = Bl + (size_t)kk*8192;
    #pragma unroll
    for(int t=0;t<16;t++){
      short8 bf = *(const short8*)(bb + t*512);
      acc[t] = __builtin_amdgcn_mfma_f32_16x16x32_bf16(af, bf, acc[t], 0, 0, 0);
    }
  }
  // D: row = rowbase + (lane>>4)*4 + r, col = t*16 + (lane&15)
  int r0 = rowbase + (lane>>4)*4;
  float dv[4]; bool ok[4];
  #pragma unroll
  for(int r=0;r<4;r++){ ok[r] = (r0+r) < M; dv[r] = ok[r] ? dinv[r0+r] : 0.f; }
  #pragma unroll
  for(int t=0;t<16;t++){
    int col = t*16 + (lane&15);
    float bc = bias[col];
    #pragma unroll
    for(int r=0;r<4;r++){
      if(ok[r]){
        float v = fmaxf(acc[t][r] + bc, 0.f) * dv[r];
        Out[(size_t)(r0+r)*256 + col] = f2bf(v);
      }
    }
  }
}

// qhat = h3hat @ W3  (K=256 -> 3), thread per row
__global__ __launch_bounds__(256) void gemm3_k(const u16* __restrict__ h3, const float* __restrict__ W3,
                        float* __restrict__ qh, int n){
  __shared__ float w3s[768];
  for(int i=threadIdx.x; i<768; i+=256) w3s[i] = W3[i];
  __syncthreads();
  int i = blockIdx.x*256 + threadIdx.x;
  if(i>=n) return;
  float a0=0.f, a1=0.f, a2=0.f;
  const uint4* hp = (const uint4*)(h3 + (size_t)i*256);
  for(int kk=0; kk<32; kk++){
    uint4 v = hp[kk];
    float f[8] = {bf_lo(v.x),bf_hi(v.x),bf_lo(v.y),bf_hi(v.y),
                  bf_lo(v.z),bf_hi(v.z),bf_lo(v.w),bf_hi(v.w)};
    int k0 = kk*8;
    #pragma unroll
    for(int j=0;j<8;j++){
      a0 += f[j]*w3s[(k0+j)*3+0];
      a1 += f[j]*w3s[(k0+j)*3+1];
      a2 += f[j]*w3s[(k0+j)*3+2];
    }
  }
  qh[i*3+0]=a0; qh[i*3+1]=a1; qh[i*3+2]=a2;
}

// p3 = A_hat qhat (3-wide) ; out = p3 + b3 + x@Wr + br
__global__ void final_k(const float* __restrict__ qh, const float* __restrict__ x,
                        const int* __restrict__ csr, const int* __restrict__ rs,
                        const int* __restrict__ deg, const float* __restrict__ dinv,
                        const float* __restrict__ b3, const float* __restrict__ Wr,
                        const float* __restrict__ br, float* __restrict__ out, int n){
  int i = blockIdx.x*256 + threadIdx.x;
  if(i>=n) return;
  float a0=0.f, a1=0.f, a2=0.f;
  int s = rs[i], e = s + deg[i];
  for(int t=s; t<e; t++){
    int c = csr[t];
    a0 += qh[c*3+0]; a1 += qh[c*3+1]; a2 += qh[c*3+2];
  }
  float di = dinv[i];
  a0 = di*(a0 + qh[i*3+0]);
  a1 = di*(a1 + qh[i*3+1]);
  a2 = di*(a2 + qh[i*3+2]);
  float x0=x[i*3+0], x1=x[i*3+1], x2=x[i*3+2];
  out[i*3+0] = a0 + b3[0] + x0*Wr[0] + x1*Wr[3] + x2*Wr[6] + br[0];
  out[i*3+1] = a1 + b3[1] + x0*Wr[1] + x1*Wr[4] + x2*Wr[7] + br[1];
  out[i*3+2] = a2 + b3[2] + x0*Wr[2] + x1*Wr[5] + x2*Wr[8] + br[2];
}

// ---------------- launch ----------------

extern "C" void kernel_launch(void* const* d_in, const int* in_sizes, int n_in,
                              void* d_out, int out_size, void* d_ws, size_t ws_size,
                              hipStream_t stream) {
  const float* x  = (const float*)d_in[0];
  const void*  ei = d_in[1];                  // int64 per reference; detect on device
  const float* W0 = (const float*)d_in[2];
  const float* b0 = (const float*)d_in[3];
  const float* W1 = (const float*)d_in[4];
  const float* b1 = (const float*)d_in[5];
  const float* W2 = (const float*)d_in[6];
  const float* b2 = (const float*)d_in[7];
  const float* W3 = (const float*)d_in[8];
  const float* b3 = (const float*)d_in[9];
  const float* Wr = (const float*)d_in[10];
  const float* br = (const float*)d_in[11];
  float* out = (float*)d_out;

  int n = in_sizes[0]/3;
  int E = in_sizes[1]/2;
  int Mpad = ((n+63)/64)*64;
  int nb = (n+1023)/1024;

  char* p = (char*)d_ws;
  auto alloc = [&](size_t bytes)->char*{ char* r=p; p += (bytes+255)&~(size_t)255; return r; };
  int*   deg   = (int*)  alloc((size_t)n*4);
  float* dinv  = (float*)alloc((size_t)n*4);
  int*   rs    = (int*)  alloc((size_t)n*4);
  int*   cur   = (int*)  alloc((size_t)n*4);
  int*   bsum  = (int*)  alloc(256*4);
  int*   flag  = (int*)  alloc(256);
  int*   csr   = (int*)  alloc((size_t)E*4);
  u16*   hA    = (u16*)  alloc((size_t)Mpad*512);
  u16*   hB    = (u16*)  alloc((size_t)Mpad*512);
  float* p0    = (float*)alloc((size_t)n*12);
  float* qh    = (float*)alloc((size_t)n*12);
  u16*   W1p   = (u16*)  alloc(65536*2);
  u16*   W2p   = (u16*)  alloc(65536*2);

  int gn  = (n+255)/256;
  int gE  = (E+255)/256;

  // graph build
  zero_k  <<<gn, 256, 0, stream>>>(deg, n);
  detect_k<<<1, 256, 0, stream>>>((const long long*)ei, flag, n, E);
  deg_k   <<<gE, 256, 0, stream>>>(ei, flag, deg, E, n);
  dinv_k  <<<gn, 256, 0, stream>>>(deg, dinv, n);
  scan1_k <<<nb, 256, 0, stream>>>(deg, bsum, n);
  scan2_k <<<1, 256, 0, stream>>>(bsum, nb);
  scan3_k <<<nb, 256, 0, stream>>>(deg, bsum, rs, cur, n);
  scat_k  <<<gE, 256, 0, stream>>>(ei, flag, cur, csr, E, n);

  // weights
  pack_k  <<<256, 256, 0, stream>>>(W1, W1p);
  pack_k  <<<256, 256, 0, stream>>>(W2, W2p);

  // layer 0: p0 = A x ; h1hat = dinv*relu(p0 W0 + b0)
  prop3_k <<<gn, 256, 0, stream>>>(x, csr, rs, deg, dinv, p0, n);
  gemm0_k <<<n, 256, 0, stream>>>(p0, W0, b0, dinv, hA, n);

  // layer 1
  prop256_k<<<(n*64+255)/256, 256, 0, stream>>>(hA, hB, csr, rs, deg, dinv, n);
  gemm256_k<<<Mpad/64, 256, 0, stream>>>(hB, W1p, b1, dinv, hA, n);

  // layer 2
  prop256_k<<<(n*64+255)/256, 256, 0, stream>>>(hA, hB, csr, rs, deg, dinv, n);
  gemm256_k<<<Mpad/64, 256, 0, stream>>>(hB, W2p, b2, dinv, hA, n);

  // layer 3 (reordered: qhat = h3hat @ W3, then 3-wide propagate) + skip
  gemm3_k <<<gn, 256, 0, stream>>>(hA, W3, qh, n);
  final_k <<<gn, 256, 0, stream>>>(qh, x, csr, rs, deg, dinv, b3, Wr, br, out, n);
}